// Round 18
// baseline (223.566 us; speedup 1.0000x reference)
//
#include <hip/hip_runtime.h>
#include <hip/hip_bf16.h>

// ---------------- problem constants ----------------
#define B_TOTAL   32768
#define L_SITES   256
#define N_MID     254        // L-2 middle sites
#define N_PAIR    127        // merged site-pairs
#define HALF_PI_F 1.57079632679489662f
#define EPS_NORM  1e-8f

// ---------------- ws layout (float/dword slots) ----------------
// [WS_FRAG .. +520191]  PAIR-table: 127 pairs x 16 frags x 64 lanes x 4 dwords
//                       frag q = c2b*4 + h*2 + pp
//                         c2b = f1*2+f2 (feature combo), h = c-half, pp: 0=hi,1=lo
//                       entries: P[a][m] with P = A_{2p,f1} @ A_{2p+1,f2} (fp32),
//                       contraction axis PI-PERMUTED (k-slot (quad,j) holds
//                       a = (j<4 ? quad*4+j : 16+quad*4+j-4)) so the swapped-MFMA
//                       output feeds the next pair with no transpose.
// [WS_C0   .. +63]      core0 fp32  [f][32]
// [WS_CN   .. +639]     coreN fp32  [f][a][10]
#define WS_FRAG 0
#define WS_C0   520192
#define WS_CN   520256

typedef short bf16x8 __attribute__((ext_vector_type(8)));
typedef float f32x4  __attribute__((ext_vector_type(4)));

// pi-permutation of the contraction axis (k-slot -> actual a index)
__device__ __host__ __forceinline__ int pi_perm(int quad, int j) {
    return (j < 4) ? (quad * 4 + j) : (16 + quad * 4 + (j - 4));
}

__device__ __forceinline__ unsigned short f2bf(float f) {
    unsigned u = __builtin_bit_cast(unsigned, f);
    u += 0x7FFFu + ((u >> 16) & 1u);          // RNE
    return (unsigned short)(u >> 16);
}
__device__ __forceinline__ float bf2f(unsigned short h) {
    unsigned u = ((unsigned)h) << 16;
    return __builtin_bit_cast(float, u);
}
__device__ __forceinline__ bf16x8 asbf(uint4 u) {
    return __builtin_bit_cast(bf16x8, u);
}
// polynomial sincos for sin(pi/2 x), cos(pi/2 x), x in [0,1].
// Taylor through x^11 / x^12: truncation <= 6e-8. Verified r11/r14/r16/r17.
__device__ __forceinline__ void psincos(float x, float* s, float* c) {
    float u = x * x;
    float sp = fmaf(u, -3.5988432352121e-6f, 1.6044118478736e-4f);
    sp = fmaf(u, sp, -4.6817541353187e-3f);
    sp = fmaf(u, sp, 7.9692626246167e-2f);
    sp = fmaf(u, sp, -6.4596409750625e-1f);
    sp = fmaf(u, sp, 1.5707963267949f);
    *s = x * sp;
    float cp = fmaf(u, 4.7108749076366e-7f, -2.5202042373061e-5f);
    cp = fmaf(u, cp, 9.1926027483943e-4f);
    cp = fmaf(u, cp, -2.0863480763353e-2f);
    cp = fmaf(u, cp, 2.5366950790105e-1f);
    cp = fmaf(u, cp, -1.2337005501362f);
    *c = fmaf(u, cp, 1.0f);
}
// packed RNE f32x2 -> bf16x2 (lowers to v_cvt_pk_bf16_f32)
__device__ __forceinline__ unsigned pkbf2(float a, float b) {
    float2 p; p.x = a; p.y = b;
    __hip_bfloat162 h2 = __float22bfloat162_rn(p);
    unsigned u;
    __builtin_memcpy(&u, &h2, 4);
    return u;                                  // a in bits 0..15, b in 16..31
}
// split 8 fp32 into hi/lo bf16 fragments via packed cvt (RNE, proven)
__device__ __forceinline__ void split8(const float* v, bf16x8& hi, bf16x8& lo) {
    uint4 H, L;
    unsigned* hp = (unsigned*)&H;
    unsigned* lp = (unsigned*)&L;
    #pragma unroll
    for (int d = 0; d < 4; ++d) {
        float a = v[2 * d], b = v[2 * d + 1];
        unsigned hb = pkbf2(a, b);
        float h0 = __builtin_bit_cast(float, hb << 16);
        float h1 = __builtin_bit_cast(float, hb & 0xFFFF0000u);
        hp[d] = hb;
        lp[d] = pkbf2(a - h0, b - h1);         // exact residuals
    }
    hi = __builtin_bit_cast(bf16x8, H);
    lo = __builtin_bit_cast(bf16x8, L);
}
// per-wave input-dtype flag: x in [0,1) -> bf16 halves always < 0x4000
__device__ __forceinline__ bool detect_bf16(const unsigned* x_raw, int lane) {
    unsigned v = x_raw[lane];
    return __ballot((v & 0xFFFFu) >= 0x4000u) == 0ull;
}

// ---------------- slim aux kernel ----------------
// blocks [0, N_PAIR) : PAIR builder (r5-verified): stage A_{2p}, A_{2p+1} in
//                      LDS (coalesced), compute P = A1@A2 per feature combo in
//                      fp32, split hi/lo, pi-permuted contraction axis.
// block  N_PAIR      : small cores -> fp32 (C0, CN).
__global__ __launch_bounds__(256)
void aux_all(const void* __restrict__ x_in, const void* __restrict__ c0_in,
             const void* __restrict__ am_in, const void* __restrict__ cn_in,
             float* __restrict__ ws) {
    const int lane = threadIdx.x & 63;
    const bool bf = detect_bf16((const unsigned*)x_in, lane);
    const int b = blockIdx.x;

    if (b < N_PAIR) {
        const int p = b;
        // a1t[f][e][a] = A_{2p}[f][a][e] (transposed for dot reads)
        // a2 [f][e][m] = A_{2p+1}[f][e][m] (linear copy)
        __shared__ float a1t[2][32][32];
        __shared__ float a2 [2][32][32];
        const unsigned short* us = (const unsigned short*)am_in;
        const float* fl = (const float*)am_in;
        for (int idx = threadIdx.x; idx < 4096; idx += 256) {
            int which = idx >> 11;              // 0: A1, 1: A2
            int off   = idx & 2047;             // [f][a][e] linear
            size_t gi = (size_t)(2 * p + which) * 2048 + off;
            float v = bf ? bf2f(us[gi]) : fl[gi];
            if (which == 0) {
                int f = off >> 10, a = (off >> 5) & 31, e = off & 31;
                a1t[f][e][a] = v;
            } else {
                ((float*)a2)[off] = v;
            }
        }
        __syncthreads();
        // compute: thread = (combo c2b = tid>>6, lane l = tid&63)
        const int l   = threadIdx.x & 63;
        const int c2b = threadIdx.x >> 6;       // f1*2+f2
        const int f1  = c2b >> 1, f2 = c2b & 1;
        const int m0  = l & 15;                 // h=0 output col
        const int m1  = 16 + (l & 15);          // h=1 output col
        unsigned H0[4], L0[4], H1[4], L1[4];
        #pragma unroll
        for (int d = 0; d < 4; ++d) {
            unsigned h0 = 0, l0 = 0, h1 = 0, l1 = 0;
            #pragma unroll
            for (int s = 0; s < 2; ++s) {
                int k = (l >> 4) * 8 + 2 * d + s;
                int a = pi_perm(k >> 3, k & 7);
                float v0 = 0.f, v1 = 0.f;
                #pragma unroll 8
                for (int e = 0; e < 32; ++e) {
                    float t = a1t[f1][e][a];
                    v0 = fmaf(t, a2[f2][e][m0], v0);
                    v1 = fmaf(t, a2[f2][e][m1], v1);
                }
                unsigned short vh0 = f2bf(v0);
                unsigned short vl0 = f2bf(v0 - bf2f(vh0));
                unsigned short vh1 = f2bf(v1);
                unsigned short vl1 = f2bf(v1 - bf2f(vh1));
                h0 |= ((unsigned)vh0) << (16 * s);
                l0 |= ((unsigned)vl0) << (16 * s);
                h1 |= ((unsigned)vh1) << (16 * s);
                l1 |= ((unsigned)vl1) << (16 * s);
            }
            H0[d] = h0; L0[d] = l0; H1[d] = h1; L1[d] = l1;
        }
        uint4* o = (uint4*)ws;
        const size_t base = ((size_t)p * 16 + c2b * 4) * 64 + l;
        uint4 u;
        u.x = H0[0]; u.y = H0[1]; u.z = H0[2]; u.w = H0[3]; o[base]       = u;  // h0 hi
        u.x = L0[0]; u.y = L0[1]; u.z = L0[2]; u.w = L0[3]; o[base + 64]  = u;  // h0 lo
        u.x = H1[0]; u.y = H1[1]; u.z = H1[2]; u.w = H1[3]; o[base + 128] = u;  // h1 hi
        u.x = L1[0]; u.y = L1[1]; u.z = L1[2]; u.w = L1[3]; o[base + 192] = u;  // h1 lo
    } else {
        for (int i = threadIdx.x; i < 640; i += 256) {
            if (i < 64)
                ws[WS_C0 + i] = bf ? bf2f(((const unsigned short*)c0_in)[i])
                                   : ((const float*)c0_in)[i];
            ws[WS_CN + i] = bf ? bf2f(((const unsigned short*)cn_in)[i])
                               : ((const float*)cn_in)[i];
        }
    }
}

// ---------------- main chain kernel ----------------
// r17 skeleton (LDS x-stage [now padded], waves_per_eu(2,2), psincos) +
// r5's PAIR math (verified passing, absmax 0.0034). Rationale: r17 counters
// show VALU-ISSUE-bound (~190 VALU insts/wave-step = 760 issue-cyc, 80%
// combined pipe busy, 7x above pure dependency latency). Pair-merge halves
// the per-site fixed step overhead (one split8, one combine, one set of
// addressing/accvgpr/bookkeeping per TWO sites) and halves serial steps;
// MFMA count and table bytes unchanged. r5's regression is attributed to its
// missing skeleton pieces (no LDS-x, no waves_per_eu, array-frag codegen) —
// here frags are 16 NAMED uint4s, plain loads, simple loop.
__global__ __launch_bounds__(256)
__attribute__((amdgpu_waves_per_eu(2, 2)))
void mps_mfma(const float* __restrict__ ws, const void* __restrict__ x_in,
              void* __restrict__ out) {
    __shared__ float xs[L_SITES][65];           // [site][b_local], padded (+1 kills
                                                // the 4-way staging-write conflict)
    const int lane = threadIdx.x & 63;
    const int w    = threadIdx.x >> 6;
    const int r    = lane & 15;
    const int quad = lane >> 4;
    const int bb   = blockIdx.x * 64;           // block's first sample
    const int bl   = w * 16 + r;                // b_local of this thread
    const int b0   = bb + w * 16;
    const uint4* __restrict__ BF = (const uint4*)ws;   // WS_FRAG = 0
    const bool bf = detect_bf16((const unsigned*)x_in, lane);

    // ---- stage x rows (coalesced) into xs[site][b_local] ----
    if (!bf) {
        const float4* x4 = (const float4*)x_in;       // row = 64 float4
        const int row = threadIdx.x >> 2;
        const int q   = threadIdx.x & 3;
        #pragma unroll
        for (int u = 0; u < 16; ++u) {
            int c4 = q + u * 4;                       // 0..63
            float4 v = x4[(size_t)(bb + row) * (L_SITES / 4) + c4];
            xs[c4 * 4 + 0][row] = v.x;
            xs[c4 * 4 + 1][row] = v.y;
            xs[c4 * 4 + 2][row] = v.z;
            xs[c4 * 4 + 3][row] = v.w;
        }
    } else {
        const uint4* x8 = (const uint4*)x_in;         // row = 32 uint4 (8 bf16)
        const int row = threadIdx.x >> 2;
        const int q   = threadIdx.x & 3;
        #pragma unroll
        for (int u = 0; u < 8; ++u) {
            int c8 = q + u * 4;                       // 0..31
            uint4 v = x8[(size_t)(bb + row) * (L_SITES / 8) + c8];
            const unsigned short* e = (const unsigned short*)&v;
            #pragma unroll
            for (int k = 0; k < 8; ++k) xs[c8 * 8 + k][row] = bf2f(e[k]);
        }
    }
    __syncthreads();

    // ---- M0 in pi-layout: mm[j] = M0[b][a=pi(quad,j)] ----
    float mm[8];
    {
        float x0 = xs[0][bl];
        float sn, cs; psincos(x0, &sn, &cs);
        const float* c0 = ws + WS_C0;
        #pragma unroll
        for (int j = 0; j < 8; ++j) {
            int a = pi_perm(quad, j);
            mm[j] = cs * c0[a] + sn * c0[32 + a];
        }
    }

    #pragma unroll 1
    for (int p = 0; p < N_PAIR; ++p) {
        // ---- 16 pair-frags, NAMED registers, plain loads ----
        const uint4* F = BF + (size_t)p * 1024 + lane;
        uint4 g0  = F[0];    uint4 g1  = F[64];   uint4 g2  = F[128];  uint4 g3  = F[192];
        uint4 g4  = F[256];  uint4 g5  = F[320];  uint4 g6  = F[384];  uint4 g7  = F[448];
        uint4 g8  = F[512];  uint4 g9  = F[576];  uint4 g10 = F[640];  uint4 g11 = F[704];
        uint4 g12 = F[768];  uint4 g13 = F[832];  uint4 g14 = F[896];  uint4 g15 = F[960];

        // ---- factors for the pair's two sites (2p+1, 2p+2) ----
        float s1, c1, s2, c2;
        psincos(xs[2 * p + 1][bl], &s1, &c1);
        psincos(xs[2 * p + 2][bl], &s2, &c2);

        // ---- split M once; 24 MFMAs as 8 independent 3-deep chains ----
        bf16x8 mh, ml;
        split8(mm, mh, ml);
        const f32x4 z = {0.f, 0.f, 0.f, 0.f};
        __builtin_amdgcn_s_setprio(1);
        f32x4 A00 = __builtin_amdgcn_mfma_f32_16x16x32_bf16(asbf(g0),  mh, z, 0, 0, 0);
        f32x4 A01 = __builtin_amdgcn_mfma_f32_16x16x32_bf16(asbf(g2),  mh, z, 0, 0, 0);
        f32x4 A10 = __builtin_amdgcn_mfma_f32_16x16x32_bf16(asbf(g4),  mh, z, 0, 0, 0);
        f32x4 A11 = __builtin_amdgcn_mfma_f32_16x16x32_bf16(asbf(g6),  mh, z, 0, 0, 0);
        f32x4 A20 = __builtin_amdgcn_mfma_f32_16x16x32_bf16(asbf(g8),  mh, z, 0, 0, 0);
        f32x4 A21 = __builtin_amdgcn_mfma_f32_16x16x32_bf16(asbf(g10), mh, z, 0, 0, 0);
        f32x4 A30 = __builtin_amdgcn_mfma_f32_16x16x32_bf16(asbf(g12), mh, z, 0, 0, 0);
        f32x4 A31 = __builtin_amdgcn_mfma_f32_16x16x32_bf16(asbf(g14), mh, z, 0, 0, 0);
        A00 = __builtin_amdgcn_mfma_f32_16x16x32_bf16(asbf(g1),  mh, A00, 0, 0, 0);
        A01 = __builtin_amdgcn_mfma_f32_16x16x32_bf16(asbf(g3),  mh, A01, 0, 0, 0);
        A10 = __builtin_amdgcn_mfma_f32_16x16x32_bf16(asbf(g5),  mh, A10, 0, 0, 0);
        A11 = __builtin_amdgcn_mfma_f32_16x16x32_bf16(asbf(g7),  mh, A11, 0, 0, 0);
        A20 = __builtin_amdgcn_mfma_f32_16x16x32_bf16(asbf(g9),  mh, A20, 0, 0, 0);
        A21 = __builtin_amdgcn_mfma_f32_16x16x32_bf16(asbf(g11), mh, A21, 0, 0, 0);
        A30 = __builtin_amdgcn_mfma_f32_16x16x32_bf16(asbf(g13), mh, A30, 0, 0, 0);
        A31 = __builtin_amdgcn_mfma_f32_16x16x32_bf16(asbf(g15), mh, A31, 0, 0, 0);
        A00 = __builtin_amdgcn_mfma_f32_16x16x32_bf16(asbf(g0),  ml, A00, 0, 0, 0);
        A01 = __builtin_amdgcn_mfma_f32_16x16x32_bf16(asbf(g2),  ml, A01, 0, 0, 0);
        A10 = __builtin_amdgcn_mfma_f32_16x16x32_bf16(asbf(g4),  ml, A10, 0, 0, 0);
        A11 = __builtin_amdgcn_mfma_f32_16x16x32_bf16(asbf(g6),  ml, A11, 0, 0, 0);
        A20 = __builtin_amdgcn_mfma_f32_16x16x32_bf16(asbf(g8),  ml, A20, 0, 0, 0);
        A21 = __builtin_amdgcn_mfma_f32_16x16x32_bf16(asbf(g10), ml, A21, 0, 0, 0);
        A30 = __builtin_amdgcn_mfma_f32_16x16x32_bf16(asbf(g12), ml, A30, 0, 0, 0);
        A31 = __builtin_amdgcn_mfma_f32_16x16x32_bf16(asbf(g14), ml, A31, 0, 0, 0);
        __builtin_amdgcn_s_setprio(0);

        // ---- 4-term post-scale combine ----
        float wcc = c1 * c2, wcs = c1 * s2, wsc = s1 * c2, wss = s1 * s2;
        #pragma unroll
        for (int j = 0; j < 4; ++j) {
            mm[j]     = fmaf(wss, A30[j], fmaf(wsc, A20[j],
                        fmaf(wcs, A10[j], wcc * A00[j])));
            mm[4 + j] = fmaf(wss, A31[j], fmaf(wsc, A21[j],
                        fmaf(wcs, A11[j], wcc * A01[j])));
        }

        // ---- normalize: pairs p%4==3 (sites 8k+7) + final pair (site 253) ----
        if (((p & 3) == 3) || (p == N_PAIR - 1)) {
            float ss = 0.f;
            #pragma unroll
            for (int j = 0; j < 8; ++j) ss = fmaf(mm[j], mm[j], ss);
            ss += __shfl_xor(ss, 16);
            ss += __shfl_xor(ss, 32);
            float kk = 1.0f / (sqrtf(ss) + EPS_NORM);
            #pragma unroll
            for (int j = 0; j < 8; ++j) mm[j] *= kk;
        }
    }

    // ---- readout: logits[r][c] = sum_a M[r][a]*(cN*KN0[a,c] + sN*KN1[a,c]) ----
    {
        float xN = xs[L_SITES - 1][bl];
        float sN, cN; psincos(xN, &sN, &cN);
        const float* kn = ws + WS_CN;        // [f][a][10]
        float acc[10];
        #pragma unroll
        for (int c = 0; c < 10; ++c) acc[c] = 0.f;
        #pragma unroll
        for (int j = 0; j < 8; ++j) {
            int a = pi_perm(quad, j);
            float Ma = mm[j];
            #pragma unroll
            for (int c = 0; c < 10; ++c) {
                float fin = cN * kn[a * 10 + c] + sN * kn[320 + a * 10 + c];
                acc[c] = fmaf(Ma, fin, acc[c]);
            }
        }
        #pragma unroll
        for (int c = 0; c < 10; ++c) {
            acc[c] += __shfl_xor(acc[c], 16);
            acc[c] += __shfl_xor(acc[c], 32);
        }
        if (quad == 0) {
            if (bf) {
                __hip_bfloat16* o = (__hip_bfloat16*)out;
                #pragma unroll
                for (int c = 0; c < 10; ++c)
                    o[(size_t)(b0 + r) * 10 + c] = __float2bfloat16(acc[c]);
            } else {
                float* o = (float*)out;
                #pragma unroll
                for (int c = 0; c < 10; ++c)
                    o[(size_t)(b0 + r) * 10 + c] = acc[c];
            }
        }
    }
}

// ---------------- launch ----------------
extern "C" void kernel_launch(void* const* d_in, const int* in_sizes, int n_in,
                              void* d_out, int out_size, void* d_ws, size_t ws_size,
                              hipStream_t stream) {
    float* ws = (float*)d_ws;
    aux_all<<<N_PAIR + 1, 256, 0, stream>>>(d_in[0], d_in[1], d_in[2], d_in[3], ws);
    // 512 blocks x 4 waves x 16 samples = 32768 samples; 2048 waves = 2 waves/SIMD
    mps_mfma<<<512, 256, 0, stream>>>(ws, d_in[0], d_out);
}